// Round 8
// baseline (1173.126 us; speedup 1.0000x reference)
//
#include <hip/hip_runtime.h>
#include <hip/hip_fp16.h>

#define NA 100000
#define NB 200000
#define MAXNB 6
#define AF 133
#define BF 147
#define H 300
#define HP 320     // padded fp16 row width for msg/amsg (640B)
#define AFP 160    // padded fp16 row width for f_bonds/f_atoms
#define NP 320     // weight N padding = BN
#define KP_C 480   // uniform K padding: [W_i(160); W_h(320)] / [atoms(160); amsg(320)]
#define BM 128
#define BN 320
#define BK 32
#define NTH 512

typedef _Float16 f16;
typedef __attribute__((ext_vector_type(8))) _Float16 f16x8;
typedef __attribute__((ext_vector_type(4))) float f32x4;

// ---- fp32 [M][Ks] -> fp16 [M][160] zero-padded ----------------------------
__global__ void conv_pad_f16(const float* __restrict__ src, f16* __restrict__ dst,
                             int M, int Ks) {
  int idx = blockIdx.x * blockDim.x + threadIdx.x;
  if (idx >= M * (AFP / 8)) return;
  int r = idx / (AFP / 8);
  int c = (idx - r * (AFP / 8)) * 8;
  f16x8 o;
#pragma unroll
  for (int j = 0; j < 8; ++j) {
    int k = c + j;
    o[j] = (k < Ks) ? (f16)src[(size_t)r * Ks + k] : (f16)0.0f;
  }
  *(f16x8*)&dst[(size_t)r * AFP + c] = o;
}

// ---- stacked [W_i; W_h] -> [n][k] fp16 ------------------------------------
__global__ void prep_w1(const float* __restrict__ Wi, const float* __restrict__ Wh,
                        f16* __restrict__ dst) {
  int idx = blockIdx.x * blockDim.x + threadIdx.x;
  if (idx >= NP * KP_C) return;
  int n = idx / KP_C, k = idx - n * KP_C;
  float v = 0.0f;
  if (n < H) {
    if (k < BF) v = Wi[(size_t)k * H + n];
    else if (k >= AFP && k < AFP + H) v = Wh[(size_t)(k - AFP) * H + n];
  }
  dst[idx] = (f16)v;
}

// ---- W_o remapped for [f_atoms(133->160 pad), amsg(300->320 pad)] ----------
__global__ void prep_wo(const float* __restrict__ src, f16* __restrict__ dst) {
  int idx = blockIdx.x * blockDim.x + threadIdx.x;
  if (idx >= NP * KP_C) return;
  int n = idx / KP_C, k = idx - n * KP_C;
  int ks = -1;
  if (k < AF) ks = k;
  else if (k >= AFP && k < AFP + H) ks = AF + (k - AFP);
  float v = (n < H && ks >= 0) ? src[(size_t)ks * H + n] : 0.0f;
  dst[idx] = (f16)v;
}

// ---- a_msg[a][:] = sum_t msg[a2b[a][t]][:] --------------------------------
__global__ void gather_sum_kernel(const f16* __restrict__ msg,
                                  const int* __restrict__ a2b,
                                  f16* __restrict__ amsg) {
  int idx = blockIdx.x * blockDim.x + threadIdx.x;
  if (idx >= NA * (HP / 8)) return;
  int a = idx / (HP / 8);
  int c = (idx - a * (HP / 8)) * 8;
  const int* nbr = &a2b[(size_t)a * MAXNB];
  float acc[8] = {0.f, 0.f, 0.f, 0.f, 0.f, 0.f, 0.f, 0.f};
#pragma unroll
  for (int t = 0; t < MAXNB; ++t) {
    int r = nbr[t];
    f16x8 v = *(const f16x8*)&msg[(size_t)r * HP + c];
#pragma unroll
    for (int j = 0; j < 8; ++j) acc[j] += (float)v[j];
  }
  f16x8 o;
#pragma unroll
  for (int j = 0; j < 8; ++j) o[j] = (f16)acc[j];
  *(f16x8*)&amsg[(size_t)a * HP + c] = o;
}

// ---- unified GEMM: 128x320 tile, 8 waves (2x4), BK=32, 16x16x32 f16 MFMA --
// Double-buffered LDS, one barrier per k-step, T14 issue-early/write-late.
// MODE 0: msg = relu(fb16 @ W_i)                                (K=160)
// MODE 1: msg' = relu([fb16[m], amsg[b2a]-msg[b2revb]] @ [W_i;W_h])  (K=480)
// MODE 2: out = relu([fa16, sum_t msg[a2b[m][t]]] @ W_o + b_o)  (K=480, fused gather)
template <int MODE>
__global__ __launch_bounds__(NTH, 4)
void gemm_kernel(const f16* __restrict__ Afp,    // fb16 (MODE 0/1) / fa16 (MODE 2)
                 const f16* __restrict__ amsg,
                 const f16* __restrict__ msg_in,
                 const int* __restrict__ b2a,
                 const int* __restrict__ b2revb,
                 const int* __restrict__ a2b,
                 const f16* __restrict__ Wp,     // stride KP_C always
                 const float* __restrict__ b_o,
                 f16* __restrict__ out_msg,
                 float* __restrict__ out_f32) {
  constexpr int KSTEPS = (MODE == 0) ? 5 : 15;
  constexpr int ASTEPS = 5;                // k-steps taken from Afp (dense rows)
  constexpr int M = (MODE == 2) ? NA : NB;

  __shared__ f16 As[2][BM][40];
  __shared__ f16 Bs[2][BN][40];

  const int mb = blockIdx.x;
  const int tid = threadIdx.x;
  const int lane = tid & 63, wid = tid >> 6;
  const int wr = wid >> 2, wc = wid & 3;   // 2 x 4 wave grid

  f32x4 acc[4][5] = {};

  // A staging: thread -> (row, 8-col chunk); one chunk per k-step
  const int arow = tid >> 2;
  const int ac = (tid & 3) * 8;
  const int m_g = mb * BM + arow;
  const int mrow = (m_g < M) ? m_g : 0;  // clamp: OOB rows masked in epilogue

  // B staging: 1280 chunks over 512 threads (3rd chunk partial)
  const int bidx2 = tid + 2 * NTH;
  const int br0 = tid >> 2,            bc0 = (tid & 3) * 8;
  const int br1 = (tid + NTH) >> 2,    bc1 = ((tid + NTH) & 3) * 8;
  const int br2 = bidx2 >> 2,          bc2 = (bidx2 & 3) * 8;
  const bool b2ok = bidx2 < BN * 4;

  int ra = 0, rb = 0;
  int nbr0 = 0, nbr1 = 0, nbr2 = 0, nbr3 = 0, nbr4 = 0, nbr5 = 0;
  if constexpr (MODE == 1) { ra = b2a[mrow]; rb = b2revb[mrow]; }
  if constexpr (MODE == 2) {
    const int* p = &a2b[(size_t)mrow * MAXNB];
    nbr0 = p[0]; nbr1 = p[1]; nbr2 = p[2]; nbr3 = p[3]; nbr4 = p[4]; nbr5 = p[5];
  }

  // raw register staging (combined only at LDS-write time -> vmcnt wait lands late)
  f16x8 ax, ay, av0, av1, av2, av3, av4, av5;
  f16x8 pw0, pw1, pw2;

  auto issue_loads = [&](int ks) {
    const int kb = ks * BK + ac;
    if constexpr (MODE == 0) {
      ax = *(const f16x8*)&Afp[(size_t)mrow * AFP + kb];
    } else if constexpr (MODE == 1) {
      if (ks < ASTEPS) {
        ax = *(const f16x8*)&Afp[(size_t)mrow * AFP + kb];
      } else {
        const int kk = kb - AFP;
        ax = *(const f16x8*)&amsg[(size_t)ra * HP + kk];
        ay = *(const f16x8*)&msg_in[(size_t)rb * HP + kk];
      }
    } else {
      if (ks < ASTEPS) {
        ax = *(const f16x8*)&Afp[(size_t)mrow * AFP + kb];
      } else {
        const int kk = kb - AFP;
        av0 = *(const f16x8*)&msg_in[(size_t)nbr0 * HP + kk];
        av1 = *(const f16x8*)&msg_in[(size_t)nbr1 * HP + kk];
        av2 = *(const f16x8*)&msg_in[(size_t)nbr2 * HP + kk];
        av3 = *(const f16x8*)&msg_in[(size_t)nbr3 * HP + kk];
        av4 = *(const f16x8*)&msg_in[(size_t)nbr4 * HP + kk];
        av5 = *(const f16x8*)&msg_in[(size_t)nbr5 * HP + kk];
      }
    }
    const int kw = ks * BK;
    pw0 = *(const f16x8*)&Wp[(size_t)br0 * KP_C + kw + bc0];
    pw1 = *(const f16x8*)&Wp[(size_t)br1 * KP_C + kw + bc1];
    if (b2ok) pw2 = *(const f16x8*)&Wp[(size_t)br2 * KP_C + kw + bc2];
  };

  auto write_lds = [&](int buf, int ks) {
    f16x8 pa;
    if constexpr (MODE == 0) {
      pa = ax;
    } else if constexpr (MODE == 1) {
      pa = (ks < ASTEPS) ? ax : (f16x8)(ax - ay);
    } else {
      if (ks < ASTEPS) {
        pa = ax;
      } else {
        f16x8 s01 = av0 + av1, s23 = av2 + av3, s45 = av4 + av5;  // v_pk_add_f16
        pa = s01 + s23 + s45;
      }
    }
    *(f16x8*)&As[buf][arow][ac] = pa;
    *(f16x8*)&Bs[buf][br0][bc0] = pw0;
    *(f16x8*)&Bs[buf][br1][bc1] = pw1;
    if (b2ok) *(f16x8*)&Bs[buf][br2][bc2] = pw2;
  };

  issue_loads(0);
  write_lds(0, 0);
  __syncthreads();

  for (int ks = 0; ks < KSTEPS; ++ks) {
    const int cur = ks & 1;
    // issue next k-step's globals BEFORE compute: latency hides under ds_read+MFMA
    if (ks + 1 < KSTEPS) issue_loads(ks + 1);

    const int row16 = lane & 15, kh = (lane >> 4) * 8;
    f16x8 af[4], bfr[5];
#pragma unroll
    for (int m = 0; m < 4; ++m)
      af[m] = *(const f16x8*)&As[cur][wr * 64 + m * 16 + row16][kh];
#pragma unroll
    for (int n = 0; n < 5; ++n)
      bfr[n] = *(const f16x8*)&Bs[cur][wc * 80 + n * 16 + row16][kh];
#pragma unroll
    for (int m = 0; m < 4; ++m)
#pragma unroll
      for (int n = 0; n < 5; ++n)
        acc[m][n] = __builtin_amdgcn_mfma_f32_16x16x32_f16(af[m], bfr[n], acc[m][n], 0, 0, 0);

    // write-late into the other buffer (vmcnt wait lands here, after MFMA)
    if (ks + 1 < KSTEPS) write_lds(cur ^ 1, ks + 1);
    __syncthreads();
  }

  // epilogue: C/D layout col = lane&15, row = (lane>>4)*4 + j  [m89]
  const int row16 = lane & 15;
  const int rquad = (lane >> 4) * 4;
#pragma unroll
  for (int m = 0; m < 4; ++m) {
#pragma unroll
    for (int n = 0; n < 5; ++n) {
      const int col = wc * 80 + n * 16 + row16;   // < 320 always
#pragma unroll
      for (int j = 0; j < 4; ++j) {
        const int row = mb * BM + wr * 64 + m * 16 + rquad + j;
        float v = acc[m][n][j];
        if constexpr (MODE == 2) {
          if (row < M && col < H)
            out_f32[(size_t)row * H + col] = fmaxf(v + b_o[col], 0.0f);
        } else {
          if (row < M)
            out_msg[(size_t)row * HP + col] = (f16)fmaxf(v, 0.0f);
        }
      }
    }
  }
}

extern "C" void kernel_launch(void* const* d_in, const int* in_sizes, int n_in,
                              void* d_out, int out_size, void* d_ws, size_t ws_size,
                              hipStream_t stream) {
  const float* f_atoms = (const float*)d_in[0];
  const float* f_bonds = (const float*)d_in[1];
  const int*   a2b     = (const int*)d_in[2];
  const int*   b2a     = (const int*)d_in[3];
  const int*   b2revb  = (const int*)d_in[4];
  const float* W_i     = (const float*)d_in[5];
  const float* W_h     = (const float*)d_in[6];
  const float* W_o     = (const float*)d_in[7];
  const float* b_o     = (const float*)d_in[8];
  float* out = (float*)d_out;

  char* ws = (char*)d_ws;
  size_t off = 0;
  f16* msgA = (f16*)(ws + off); off += (size_t)NB * HP * 2;   // 128.0 MB
  f16* msgB = (f16*)(ws + off); off += (size_t)NB * HP * 2;   // 128.0 MB
  f16* amsg = (f16*)(ws + off); off += (size_t)NA * HP * 2;   //  64.0 MB
  f16* fb16 = (f16*)(ws + off); off += (size_t)NB * AFP * 2;  //  64.0 MB
  f16* fa16 = (f16*)(ws + off); off += (size_t)NA * AFP * 2;  //  32.0 MB
  f16* W1P  = (f16*)(ws + off); off += (size_t)NP * KP_C * 2;
  f16* WoP  = (f16*)(ws + off); off += (size_t)NP * KP_C * 2;
  if (off > ws_size) return;  // total ~416.6 MB

  prep_w1<<<(NP * KP_C + 255) / 256, 256, 0, stream>>>(W_i, W_h, W1P);
  prep_wo<<<(NP * KP_C + 255) / 256, 256, 0, stream>>>(W_o, WoP);
  conv_pad_f16<<<(NB * (AFP / 8) + 255) / 256, 256, 0, stream>>>(f_bonds, fb16, NB, BF);
  conv_pad_f16<<<(NA * (AFP / 8) + 255) / 256, 256, 0, stream>>>(f_atoms, fa16, NA, AF);

  const int gB = (NB + BM - 1) / BM;   // 1563
  const int gA = (NA + BM - 1) / BM;   // 782
  dim3 gS((NA * (HP / 8) + 255) / 256);

  // msgA = relu(fb16 @ W_i)
  gemm_kernel<0><<<gB, NTH, 0, stream>>>(fb16, nullptr, nullptr,
                                         nullptr, nullptr, nullptr, W1P, nullptr,
                                         msgA, nullptr);
  // iteration 1: msgB = relu(inp + (amsg[b2a]-msgA[b2revb]) @ W_h)  [fused]
  gather_sum_kernel<<<gS, 256, 0, stream>>>(msgA, a2b, amsg);
  gemm_kernel<1><<<gB, NTH, 0, stream>>>(fb16, amsg, msgA,
                                         b2a, b2revb, nullptr, W1P, nullptr,
                                         msgB, nullptr);
  // iteration 2
  gather_sum_kernel<<<gS, 256, 0, stream>>>(msgB, a2b, amsg);
  gemm_kernel<1><<<gB, NTH, 0, stream>>>(fb16, amsg, msgB,
                                         b2a, b2revb, nullptr, W1P, nullptr,
                                         msgA, nullptr);
  // readout: gather fused into the GEMM A-load
  gemm_kernel<2><<<gA, NTH, 0, stream>>>(fa16, nullptr, msgA,
                                         nullptr, nullptr, a2b, WoP, b_o,
                                         nullptr, out);
}

// Round 9
// 902.884 us; speedup vs baseline: 1.2993x; 1.2993x over previous
//
#include <hip/hip_runtime.h>
#include <hip/hip_fp16.h>

#define NA 100000
#define NB 200000
#define MAXNB 6
#define AF 133
#define BF 147
#define H 300
#define HP 320     // padded fp16 row width for msg/amsg (640B)
#define AFP 160    // padded fp16 row width for f_bonds/f_atoms
#define NP 320     // weight N padding = BN
#define KPW 512    // weight K stride: [W_i(160); W_h(300); 0-pad]
#define BM 128
#define BN 320
#define BK 64
#define NTH 512
#define LDK 72     // LDS row stride (64 + 8 pad): 144B rows -> 2-way conflicts only

typedef _Float16 f16;
typedef __attribute__((ext_vector_type(8))) _Float16 f16x8;
typedef __attribute__((ext_vector_type(4))) float f32x4;

// ---- fp32 [M][Ks] -> fp16 [M][160] zero-padded ----------------------------
__global__ void conv_pad_f16(const float* __restrict__ src, f16* __restrict__ dst,
                             int M, int Ks) {
  int idx = blockIdx.x * blockDim.x + threadIdx.x;
  if (idx >= M * (AFP / 8)) return;
  int r = idx / (AFP / 8);
  int c = (idx - r * (AFP / 8)) * 8;
  f16x8 o;
#pragma unroll
  for (int j = 0; j < 8; ++j) {
    int k = c + j;
    o[j] = (k < Ks) ? (f16)src[(size_t)r * Ks + k] : (f16)0.0f;
  }
  *(f16x8*)&dst[(size_t)r * AFP + c] = o;
}

// ---- stacked [W_i; W_h] -> [n][k] fp16, stride KPW -------------------------
__global__ void prep_w1(const float* __restrict__ Wi, const float* __restrict__ Wh,
                        f16* __restrict__ dst) {
  int idx = blockIdx.x * blockDim.x + threadIdx.x;
  if (idx >= NP * KPW) return;
  int n = idx / KPW, k = idx - n * KPW;
  float v = 0.0f;
  if (n < H) {
    if (k < BF) v = Wi[(size_t)k * H + n];
    else if (k >= AFP && k < AFP + H) v = Wh[(size_t)(k - AFP) * H + n];
  }
  dst[idx] = (f16)v;
}

// ---- W_o remapped for [f_atoms(133->160 pad), amsg(300->320+ pad)] ---------
__global__ void prep_wo(const float* __restrict__ src, f16* __restrict__ dst) {
  int idx = blockIdx.x * blockDim.x + threadIdx.x;
  if (idx >= NP * KPW) return;
  int n = idx / KPW, k = idx - n * KPW;
  int ks = -1;
  if (k < AF) ks = k;
  else if (k >= AFP && k < AFP + H) ks = AF + (k - AFP);
  float v = (n < H && ks >= 0) ? src[(size_t)ks * H + n] : 0.0f;
  dst[idx] = (f16)v;
}

// ---- a_msg[a][:] = sum_t msg[a2b[a][t]][:] --------------------------------
__global__ void gather_sum_kernel(const f16* __restrict__ msg,
                                  const int* __restrict__ a2b,
                                  f16* __restrict__ amsg) {
  int idx = blockIdx.x * blockDim.x + threadIdx.x;
  if (idx >= NA * (HP / 8)) return;
  int a = idx / (HP / 8);
  int c = (idx - a * (HP / 8)) * 8;
  const int* nbr = &a2b[(size_t)a * MAXNB];
  float acc[8] = {0.f, 0.f, 0.f, 0.f, 0.f, 0.f, 0.f, 0.f};
#pragma unroll
  for (int t = 0; t < MAXNB; ++t) {
    int r = nbr[t];
    f16x8 v = *(const f16x8*)&msg[(size_t)r * HP + c];
#pragma unroll
    for (int j = 0; j < 8; ++j) acc[j] += (float)v[j];
  }
  f16x8 o;
#pragma unroll
  for (int j = 0; j < 8; ++j) o[j] = (f16)acc[j];
  *(f16x8*)&amsg[(size_t)a * HP + c] = o;
}

// ---- unified GEMM: 128x320 tile, 8 waves (2x4), BK=64, dbuf LDS -----------
// One barrier per k-step; loads issued ~1.5 iterations ahead of consumption.
// MODE 0: msg = relu(fb16 @ W_i)                       (K=160, 2.5 steps)
// MODE 1: msg' = relu([fb16[m], amsg[b2a]-msg[b2revb]] @ [W_i;W_h])  (K=512)
// MODE 2: out = relu([fa16, amsg(dense)] @ W_o + b_o)  (K=512, fp32 out)
template <int MODE>
__global__ __launch_bounds__(NTH)
void gemm_kernel(const f16* __restrict__ Afp,    // fb16 (MODE 0/1) / fa16 (MODE 2)
                 const f16* __restrict__ amsg,   // MODE1: gathered; MODE2: dense
                 const f16* __restrict__ msg_in, // MODE1 only
                 const int* __restrict__ b2a,
                 const int* __restrict__ b2revb,
                 const f16* __restrict__ Wp,     // [NP][KPW]
                 const float* __restrict__ b_o,
                 f16* __restrict__ out_msg,
                 float* __restrict__ out_f32) {
  constexpr int KSTEPS = (MODE == 0) ? 3 : 8;
  constexpr int M = (MODE == 2) ? NA : NB;

  __shared__ f16 As[2][BM][LDK];
  __shared__ f16 Bs[2][BN][LDK];

  const int mb = blockIdx.x;
  const int tid = threadIdx.x;
  const int lane = tid & 63, wid = tid >> 6;
  const int wr = wid >> 2, wc = wid & 3;   // 2 x 4 wave grid

  f32x4 acc[4][5] = {};

  // A staging: 1024 8-elem chunks; thread -> row tid>>2, cols [(tid&3)*16, +16)
  const int arow = tid >> 2;
  const int ac0 = (tid & 3) * 16;
  const int m_g = mb * BM + arow;
  const int mrow = (m_g < M) ? m_g : 0;  // clamp: OOB rows masked in epilogue

  // B staging: 2560 chunks, 5 per thread: slot = tid + j*NTH
  int brow[5], bcol[5];
#pragma unroll
  for (int j = 0; j < 5; ++j) {
    int s = tid + j * NTH;
    brow[j] = s >> 3; bcol[j] = (s & 7) * 8;
  }

  int ra = 0, rb = 0;
  if constexpr (MODE == 1) { ra = b2a[mrow]; rb = b2revb[mrow]; }

  // stage registers (one set in flight)
  f16x8 ax0, ax1, ay0, ay1, pw[5];
  const f16x8 zz = {0, 0, 0, 0, 0, 0, 0, 0};

  auto issue_loads = [&](int ks) {
    const int kb0 = ks * BK + ac0;
    const int kb1 = kb0 + 8;
    if constexpr (MODE == 0) {
      ax0 = (kb0 < AFP) ? *(const f16x8*)&Afp[(size_t)mrow * AFP + kb0] : zz;
      ax1 = (kb1 < AFP) ? *(const f16x8*)&Afp[(size_t)mrow * AFP + kb1] : zz;
    } else if constexpr (MODE == 1) {
      if (kb0 < AFP) ax0 = *(const f16x8*)&Afp[(size_t)mrow * AFP + kb0];
      else { ax0 = *(const f16x8*)&amsg[(size_t)ra * HP + (kb0 - AFP)];
             ay0 = *(const f16x8*)&msg_in[(size_t)rb * HP + (kb0 - AFP)]; }
      if (kb1 < AFP) ax1 = *(const f16x8*)&Afp[(size_t)mrow * AFP + kb1];
      else { ax1 = *(const f16x8*)&amsg[(size_t)ra * HP + (kb1 - AFP)];
             ay1 = *(const f16x8*)&msg_in[(size_t)rb * HP + (kb1 - AFP)]; }
    } else {
      ax0 = (kb0 < AFP) ? *(const f16x8*)&Afp[(size_t)mrow * AFP + kb0]
                        : *(const f16x8*)&amsg[(size_t)mrow * HP + (kb0 - AFP)];
      ax1 = (kb1 < AFP) ? *(const f16x8*)&Afp[(size_t)mrow * AFP + kb1]
                        : *(const f16x8*)&amsg[(size_t)mrow * HP + (kb1 - AFP)];
    }
    const int kw = ks * BK;
#pragma unroll
    for (int j = 0; j < 5; ++j)
      pw[j] = *(const f16x8*)&Wp[(size_t)brow[j] * KPW + kw + bcol[j]];
  };

  auto write_lds = [&](int ks) {
    const int buf = ks & 1;
    const int kb0 = ks * BK + ac0;
    f16x8 pa0 = ax0, pa1 = ax1;
    if constexpr (MODE == 1) {
      if (kb0 >= AFP) pa0 = ax0 - ay0;
      if (kb0 + 8 >= AFP) pa1 = ax1 - ay1;
    }
    *(f16x8*)&As[buf][arow][ac0]     = pa0;
    *(f16x8*)&As[buf][arow][ac0 + 8] = pa1;
#pragma unroll
    for (int j = 0; j < 5; ++j)
      *(f16x8*)&Bs[buf][brow[j]][bcol[j]] = pw[j];
  };

  issue_loads(0);
  write_lds(0);
  issue_loads(1);          // in flight across the barrier + next compute phase
  __syncthreads();

  const int row16 = lane & 15, k8 = (lane >> 4) * 8;

  for (int ks = 0; ks < KSTEPS; ++ks) {
    const int cur = ks & 1;
#pragma unroll
    for (int h = 0; h < 2; ++h) {
      if (MODE == 0 && ks == 2 && h == 1) break;  // K=160: skip zero tail
      const int kc = h * 32 + k8;
      f16x8 bfr[5];
#pragma unroll
      for (int n = 0; n < 5; ++n)
        bfr[n] = *(const f16x8*)&Bs[cur][wc * 80 + n * 16 + row16][kc];
#pragma unroll
      for (int mp = 0; mp < 2; ++mp) {
        f16x8 af0 = *(const f16x8*)&As[cur][wr * 64 + (mp * 2) * 16 + row16][kc];
        f16x8 af1 = *(const f16x8*)&As[cur][wr * 64 + (mp * 2 + 1) * 16 + row16][kc];
#pragma unroll
        for (int n = 0; n < 5; ++n) {
          acc[mp * 2][n]     = __builtin_amdgcn_mfma_f32_16x16x32_f16(af0, bfr[n], acc[mp * 2][n], 0, 0, 0);
          acc[mp * 2 + 1][n] = __builtin_amdgcn_mfma_f32_16x16x32_f16(af1, bfr[n], acc[mp * 2 + 1][n], 0, 0, 0);
        }
      }
    }
    // write next tile (vmcnt wait lands here, after MFMA), then start ks+2
    if (ks + 1 < KSTEPS) write_lds(ks + 1);
    if (ks + 2 < KSTEPS) issue_loads(ks + 2);
    __syncthreads();
  }

  // epilogue: C/D layout col = lane&15, row = (lane>>4)*4 + j  [m89]
  const int rquad = (lane >> 4) * 4;
#pragma unroll
  for (int m = 0; m < 4; ++m) {
#pragma unroll
    for (int n = 0; n < 5; ++n) {
      const int col = wc * 80 + n * 16 + row16;   // < 320 always
#pragma unroll
      for (int j = 0; j < 4; ++j) {
        const int row = mb * BM + wr * 64 + m * 16 + rquad + j;
        float v = acc[m][n][j];
        if constexpr (MODE == 2) {
          if (row < M && col < H)
            out_f32[(size_t)row * H + col] = fmaxf(v + b_o[col], 0.0f);
        } else {
          if (row < M)
            out_msg[(size_t)row * HP + col] = (f16)fmaxf(v, 0.0f);
        }
      }
    }
  }
}

extern "C" void kernel_launch(void* const* d_in, const int* in_sizes, int n_in,
                              void* d_out, int out_size, void* d_ws, size_t ws_size,
                              hipStream_t stream) {
  const float* f_atoms = (const float*)d_in[0];
  const float* f_bonds = (const float*)d_in[1];
  const int*   a2b     = (const int*)d_in[2];
  const int*   b2a     = (const int*)d_in[3];
  const int*   b2revb  = (const int*)d_in[4];
  const float* W_i     = (const float*)d_in[5];
  const float* W_h     = (const float*)d_in[6];
  const float* W_o     = (const float*)d_in[7];
  const float* b_o     = (const float*)d_in[8];
  float* out = (float*)d_out;

  char* ws = (char*)d_ws;
  size_t off = 0;
  f16* msgA = (f16*)(ws + off); off += (size_t)NB * HP * 2;   // 128.0 MB
  f16* msgB = (f16*)(ws + off); off += (size_t)NB * HP * 2;   // 128.0 MB
  f16* amsg = (f16*)(ws + off); off += (size_t)NA * HP * 2;   //  64.0 MB
  f16* fb16 = (f16*)(ws + off); off += (size_t)NB * AFP * 2;  //  64.0 MB
  f16* fa16 = (f16*)(ws + off); off += (size_t)NA * AFP * 2;  //  32.0 MB
  f16* W1P  = (f16*)(ws + off); off += (size_t)NP * KPW * 2;
  f16* WoP  = (f16*)(ws + off); off += (size_t)NP * KPW * 2;
  if (off > ws_size) return;  // total ~417 MB

  prep_w1<<<(NP * KPW + 255) / 256, 256, 0, stream>>>(W_i, W_h, W1P);
  prep_wo<<<(NP * KPW + 255) / 256, 256, 0, stream>>>(W_o, WoP);
  conv_pad_f16<<<(NB * (AFP / 8) + 255) / 256, 256, 0, stream>>>(f_bonds, fb16, NB, BF);
  conv_pad_f16<<<(NA * (AFP / 8) + 255) / 256, 256, 0, stream>>>(f_atoms, fa16, NA, AF);

  const int gB = (NB + BM - 1) / BM;   // 1563
  const int gA = (NA + BM - 1) / BM;   // 782
  dim3 gS((NA * (HP / 8) + 255) / 256);

  // msgA = relu(fb16 @ W_i)
  gemm_kernel<0><<<gB, NTH, 0, stream>>>(fb16, nullptr, nullptr,
                                         nullptr, nullptr, W1P, nullptr,
                                         msgA, nullptr);
  // iteration 1: msgB = relu(inp + (amsg[b2a]-msgA[b2revb]) @ W_h)  [fused]
  gather_sum_kernel<<<gS, 256, 0, stream>>>(msgA, a2b, amsg);
  gemm_kernel<1><<<gB, NTH, 0, stream>>>(fb16, amsg, msgA,
                                         b2a, b2revb, W1P, nullptr,
                                         msgB, nullptr);
  // iteration 2
  gather_sum_kernel<<<gS, 256, 0, stream>>>(msgB, a2b, amsg);
  gemm_kernel<1><<<gB, NTH, 0, stream>>>(fb16, amsg, msgB,
                                         b2a, b2revb, W1P, nullptr,
                                         msgA, nullptr);
  // readout: gather separately (streaming, high-occupancy), dense GEMM
  gather_sum_kernel<<<gS, 256, 0, stream>>>(msgA, a2b, amsg);
  gemm_kernel<2><<<gA, NTH, 0, stream>>>(fa16, amsg, nullptr,
                                         nullptr, nullptr, WoP, b_o,
                                         nullptr, out);
}

// Round 10
// 733.369 us; speedup vs baseline: 1.5996x; 1.2311x over previous
//
#include <hip/hip_runtime.h>
#include <hip/hip_fp16.h>

#define NA 100000
#define NB 200000
#define MAXNB 6
#define AF 133
#define BF 147
#define H 300
#define HP 320     // padded fp16 row width for msg/amsg (640B)
#define AFP 160    // padded fp16 row width for f_bonds/f_atoms
#define NP 320     // weight N padding = BN
#define KP_C 480   // uniform K padding: [W_i(160); W_h(320)] / [atoms(160); amsg(320)]
#define BM 128
#define BN 320
#define BK 32
#define NTH 512
#define LDK 40     // LDS row stride (32 + 8 pad): 80B rows -> 2-way conflicts max

typedef _Float16 f16;
typedef __attribute__((ext_vector_type(8))) _Float16 f16x8;
typedef __attribute__((ext_vector_type(4))) float f32x4;

// ---- fp32 [M][Ks] -> fp16 [M][160] zero-padded ----------------------------
__global__ void conv_pad_f16(const float* __restrict__ src, f16* __restrict__ dst,
                             int M, int Ks) {
  int idx = blockIdx.x * blockDim.x + threadIdx.x;
  if (idx >= M * (AFP / 8)) return;
  int r = idx / (AFP / 8);
  int c = (idx - r * (AFP / 8)) * 8;
  f16x8 o;
#pragma unroll
  for (int j = 0; j < 8; ++j) {
    int k = c + j;
    o[j] = (k < Ks) ? (f16)src[(size_t)r * Ks + k] : (f16)0.0f;
  }
  *(f16x8*)&dst[(size_t)r * AFP + c] = o;
}

// ---- stacked [W_i; W_h] -> [n][k] fp16, stride KP_C ------------------------
__global__ void prep_w1(const float* __restrict__ Wi, const float* __restrict__ Wh,
                        f16* __restrict__ dst) {
  int idx = blockIdx.x * blockDim.x + threadIdx.x;
  if (idx >= NP * KP_C) return;
  int n = idx / KP_C, k = idx - n * KP_C;
  float v = 0.0f;
  if (n < H) {
    if (k < BF) v = Wi[(size_t)k * H + n];
    else if (k >= AFP && k < AFP + H) v = Wh[(size_t)(k - AFP) * H + n];
  }
  dst[idx] = (f16)v;
}

// ---- W_o remapped for [f_atoms(133->160 pad), amsg(300->320 pad)] ----------
__global__ void prep_wo(const float* __restrict__ src, f16* __restrict__ dst) {
  int idx = blockIdx.x * blockDim.x + threadIdx.x;
  if (idx >= NP * KP_C) return;
  int n = idx / KP_C, k = idx - n * KP_C;
  int ks = -1;
  if (k < AF) ks = k;
  else if (k >= AFP && k < AFP + H) ks = AF + (k - AFP);
  float v = (n < H && ks >= 0) ? src[(size_t)ks * H + n] : 0.0f;
  dst[idx] = (f16)v;
}

// ---- a_msg[a][:] = sum_t msg[a2b[a][t]][:] --------------------------------
__global__ void gather_sum_kernel(const f16* __restrict__ msg,
                                  const int* __restrict__ a2b,
                                  f16* __restrict__ amsg) {
  int idx = blockIdx.x * blockDim.x + threadIdx.x;
  if (idx >= NA * (HP / 8)) return;
  int a = idx / (HP / 8);
  int c = (idx - a * (HP / 8)) * 8;
  const int* nbr = &a2b[(size_t)a * MAXNB];
  float acc[8] = {0.f, 0.f, 0.f, 0.f, 0.f, 0.f, 0.f, 0.f};
#pragma unroll
  for (int t = 0; t < MAXNB; ++t) {
    int r = nbr[t];
    f16x8 v = *(const f16x8*)&msg[(size_t)r * HP + c];
#pragma unroll
    for (int j = 0; j < 8; ++j) acc[j] += (float)v[j];
  }
  f16x8 o;
#pragma unroll
  for (int j = 0; j < 8; ++j) o[j] = (f16)acc[j];
  *(f16x8*)&amsg[(size_t)a * HP + c] = o;
}

// ---- unified GEMM: 128x320 tile, 8 waves (2x4), BK=32, dbuf LDS -----------
// ONE barrier per k-step; loads issued ~1.5 iterations before consumption.
// MODE 0: msg = relu(fb16 @ W_i)                                (K=160)
// MODE 1: msg' = relu([fb16[m], amsg[b2a]-msg[b2revb]] @ [W_i;W_h])  (K=480)
// MODE 2: out = relu([fa16, amsg(dense)] @ W_o + b_o)           (K=480)
template <int MODE>
__global__ __launch_bounds__(NTH)
void gemm_kernel(const f16* __restrict__ Afp,    // fb16 (MODE 0/1) / fa16 (MODE 2)
                 const f16* __restrict__ amsg,   // MODE1: gathered; MODE2: dense
                 const f16* __restrict__ msg_in, // MODE1 only
                 const int* __restrict__ b2a,
                 const int* __restrict__ b2revb,
                 const f16* __restrict__ Wp,     // [NP][KP_C]
                 const float* __restrict__ b_o,
                 f16* __restrict__ out_msg,
                 float* __restrict__ out_f32) {
  constexpr int KSTEPS = (MODE == 0) ? 5 : 15;
  constexpr int ASTEPS = 5;                // k-steps sourced from Afp
  constexpr int M = (MODE == 2) ? NA : NB;

  __shared__ f16 As[2][BM][LDK];
  __shared__ f16 Bs[2][BN][LDK];

  const int mb = blockIdx.x;
  const int tid = threadIdx.x;
  const int lane = tid & 63, wid = tid >> 6;
  const int wr = wid >> 2, wc = wid & 3;   // 2 x 4 wave grid

  f32x4 acc[4][5] = {};

  // A staging: 512 8-elem chunks == NTH; thread -> (tid>>2, (tid&3)*8)
  const int arow = tid >> 2;
  const int ac = (tid & 3) * 8;
  const int m_g = mb * BM + arow;
  const int mrow = (m_g < M) ? m_g : 0;  // clamp: OOB rows masked in epilogue

  // B staging: 1280 chunks over 512 threads (3rd chunk partial, tid<256)
  const int bidx2 = tid + 2 * NTH;
  const int br0 = tid >> 2,            bc0 = (tid & 3) * 8;
  const int br1 = (tid + NTH) >> 2,    bc1 = ((tid + NTH) & 3) * 8;
  const int br2 = bidx2 >> 2,          bc2 = (bidx2 & 3) * 8;
  const bool b2ok = bidx2 < BN * 4;

  int ra = 0, rb = 0;
  if constexpr (MODE == 1) { ra = b2a[mrow]; rb = b2revb[mrow]; }

  // single staging set: live only from issue to the following write_lds
  f16x8 ax, ay, pw0, pw1, pw2;

  auto issue_loads = [&](int ks) {
    const int kb = ks * BK + ac;
    if constexpr (MODE == 0) {
      ax = *(const f16x8*)&Afp[(size_t)mrow * AFP + kb];
    } else if constexpr (MODE == 1) {
      if (ks < ASTEPS) {
        ax = *(const f16x8*)&Afp[(size_t)mrow * AFP + kb];
      } else {
        const int kk = kb - AFP;
        ax = *(const f16x8*)&amsg[(size_t)ra * HP + kk];
        ay = *(const f16x8*)&msg_in[(size_t)rb * HP + kk];
      }
    } else {
      ax = (ks < ASTEPS) ? *(const f16x8*)&Afp[(size_t)mrow * AFP + kb]
                         : *(const f16x8*)&amsg[(size_t)mrow * HP + (kb - AFP)];
    }
    const int kw = ks * BK;
    pw0 = *(const f16x8*)&Wp[(size_t)br0 * KP_C + kw + bc0];
    pw1 = *(const f16x8*)&Wp[(size_t)br1 * KP_C + kw + bc1];
    if (b2ok) pw2 = *(const f16x8*)&Wp[(size_t)br2 * KP_C + kw + bc2];
  };

  auto write_lds = [&](int buf, int ks) {
    f16x8 pa = ax;
    if constexpr (MODE == 1) {
      if (ks >= ASTEPS) pa = ax - ay;
    }
    *(f16x8*)&As[buf][arow][ac] = pa;
    *(f16x8*)&Bs[buf][br0][bc0] = pw0;
    *(f16x8*)&Bs[buf][br1][bc1] = pw1;
    if (b2ok) *(f16x8*)&Bs[buf][br2][bc2] = pw2;
  };

  issue_loads(0);
  write_lds(0, 0);
  issue_loads(1);          // in flight across barrier + compute(0)
  __syncthreads();

  const int row16 = lane & 15, kh = (lane >> 4) * 8;

  for (int ks = 0; ks < KSTEPS; ++ks) {
    const int cur = ks & 1;
    f16x8 af[4], bfr[5];
#pragma unroll
    for (int m = 0; m < 4; ++m)
      af[m] = *(const f16x8*)&As[cur][wr * 64 + m * 16 + row16][kh];
#pragma unroll
    for (int n = 0; n < 5; ++n)
      bfr[n] = *(const f16x8*)&Bs[cur][wc * 80 + n * 16 + row16][kh];
#pragma unroll
    for (int m = 0; m < 4; ++m)
#pragma unroll
      for (int n = 0; n < 5; ++n)
        acc[m][n] = __builtin_amdgcn_mfma_f32_16x16x32_f16(af[m], bfr[n], acc[m][n], 0, 0, 0);

    // write next tile into the other buffer (vmcnt wait lands here, post-MFMA),
    // then immediately issue loads for ks+2 (covered by compute(ks+1))
    if (ks + 1 < KSTEPS) write_lds(cur ^ 1, ks + 1);
    if (ks + 2 < KSTEPS) issue_loads(ks + 2);
    __syncthreads();
  }

  // epilogue: C/D layout col = lane&15, row = (lane>>4)*4 + j  [m89]
  const int rquad = (lane >> 4) * 4;
#pragma unroll
  for (int m = 0; m < 4; ++m) {
#pragma unroll
    for (int n = 0; n < 5; ++n) {
      const int col = wc * 80 + n * 16 + row16;   // < 320 always
#pragma unroll
      for (int j = 0; j < 4; ++j) {
        const int row = mb * BM + wr * 64 + m * 16 + rquad + j;
        float v = acc[m][n][j];
        if constexpr (MODE == 2) {
          if (row < M && col < H)
            out_f32[(size_t)row * H + col] = fmaxf(v + b_o[col], 0.0f);
        } else {
          if (row < M)
            out_msg[(size_t)row * HP + col] = (f16)fmaxf(v, 0.0f);
        }
      }
    }
  }
}

extern "C" void kernel_launch(void* const* d_in, const int* in_sizes, int n_in,
                              void* d_out, int out_size, void* d_ws, size_t ws_size,
                              hipStream_t stream) {
  const float* f_atoms = (const float*)d_in[0];
  const float* f_bonds = (const float*)d_in[1];
  const int*   a2b     = (const int*)d_in[2];
  const int*   b2a     = (const int*)d_in[3];
  const int*   b2revb  = (const int*)d_in[4];
  const float* W_i     = (const float*)d_in[5];
  const float* W_h     = (const float*)d_in[6];
  const float* W_o     = (const float*)d_in[7];
  const float* b_o     = (const float*)d_in[8];
  float* out = (float*)d_out;

  char* ws = (char*)d_ws;
  size_t off = 0;
  f16* msgA = (f16*)(ws + off); off += (size_t)NB * HP * 2;   // 128.0 MB
  f16* msgB = (f16*)(ws + off); off += (size_t)NB * HP * 2;   // 128.0 MB
  f16* amsg = (f16*)(ws + off); off += (size_t)NA * HP * 2;   //  64.0 MB
  f16* fb16 = (f16*)(ws + off); off += (size_t)NB * AFP * 2;  //  64.0 MB
  f16* fa16 = (f16*)(ws + off); off += (size_t)NA * AFP * 2;  //  32.0 MB
  f16* W1P  = (f16*)(ws + off); off += (size_t)NP * KP_C * 2;
  f16* WoP  = (f16*)(ws + off); off += (size_t)NP * KP_C * 2;
  if (off > ws_size) return;  // total ~416.6 MB

  prep_w1<<<(NP * KP_C + 255) / 256, 256, 0, stream>>>(W_i, W_h, W1P);
  prep_wo<<<(NP * KP_C + 255) / 256, 256, 0, stream>>>(W_o, WoP);
  conv_pad_f16<<<(NB * (AFP / 8) + 255) / 256, 256, 0, stream>>>(f_bonds, fb16, NB, BF);
  conv_pad_f16<<<(NA * (AFP / 8) + 255) / 256, 256, 0, stream>>>(f_atoms, fa16, NA, AF);

  const int gB = (NB + BM - 1) / BM;   // 1563
  const int gA = (NA + BM - 1) / BM;   // 782
  dim3 gS((NA * (HP / 8) + 255) / 256);

  // msgA = relu(fb16 @ W_i)
  gemm_kernel<0><<<gB, NTH, 0, stream>>>(fb16, nullptr, nullptr,
                                         nullptr, nullptr, W1P, nullptr,
                                         msgA, nullptr);
  // iteration 1: msgB = relu(inp + (amsg[b2a]-msgA[b2revb]) @ W_h)  [fused]
  gather_sum_kernel<<<gS, 256, 0, stream>>>(msgA, a2b, amsg);
  gemm_kernel<1><<<gB, NTH, 0, stream>>>(fb16, amsg, msgA,
                                         b2a, b2revb, W1P, nullptr,
                                         msgB, nullptr);
  // iteration 2
  gather_sum_kernel<<<gS, 256, 0, stream>>>(msgB, a2b, amsg);
  gemm_kernel<1><<<gB, NTH, 0, stream>>>(fb16, amsg, msgB,
                                         b2a, b2revb, W1P, nullptr,
                                         msgA, nullptr);
  // readout: gather separately (streaming, high-occupancy), dense GEMM
  gather_sum_kernel<<<gS, 256, 0, stream>>>(msgA, a2b, amsg);
  gemm_kernel<2><<<gA, NTH, 0, stream>>>(fa16, amsg, nullptr,
                                         nullptr, nullptr, WoP, b_o,
                                         nullptr, out);
}